// Round 12
// baseline (231.919 us; speedup 1.0000x reference)
//
#include <hip/hip_runtime.h>
#include <hip/hip_bf16.h>

#define T_LEN 1024
#define NH    16
#define CH    64
#define LSTR  64        // Q-prologue LDS row stride in shorts (128 B)
#define FSTR  520       // fragment stride in shorts (512 + 8 pad)
#define VOFF  (8 * FSTR)   // one K-or-V buffer in shorts (4160 = 8320 B)

typedef __attribute__((ext_vector_type(8))) short short8;
typedef __attribute__((ext_vector_type(4))) float floatx4;
typedef unsigned long long u64;

__device__ __forceinline__ short f2bf(float x) {
    __hip_bfloat16 b = __float2bfloat16(x);   // RNE (prologue-only scalar path)
    return *(short*)&b;
}
// HW packed conversion: dst.lo16 = bf16(lo), dst.hi16 = bf16(hi).
__device__ __forceinline__ unsigned cvt_pk_bf16(float lo, float hi) {
    unsigned r;
    asm("v_cvt_pk_bf16_f32 %0, %1, %2" : "=v"(r) : "v"(lo), "v"(hi));
    return r;
}
// XOR block-swizzle for the Q prologue tile (stride-64-short rows).
__device__ __forceinline__ int fsw(int row) {
    return (((row & 7) ^ ((row >> 3) & 7)) << 3);
}
// K-row permutation (r6+): physical s-row kperm(s) makes the swapped
// QK^T output land so the PV A-frag assembles in-register.
__device__ __forceinline__ int kperm(int s) {
    return (s & 0x23) | ((s & 0x18) >> 1) | ((s & 4) << 2);
}
// Block-placement XOR-fold (r9): frag reads + b128 writes conflict-free.
__device__ __forceinline__ int bfold(int bi) {
    return bi ^ ((bi >> 3) & 7);
}

// ---- mask bit-pack: (8,1024,1024) int32 -> (8,1024,16) u64 via wave ballot ----
__global__ __launch_bounds__(256)
void pack_mask_kernel(const int* __restrict__ mask, u64* __restrict__ pm)
{
    const int NW = 8 * T_LEN * (T_LEN / 64);   // 131072 words
    const int lane = threadIdx.x & 63;
    const int gw = (int)((blockIdx.x * blockDim.x + threadIdx.x) >> 6);
    const int nw = (int)((gridDim.x * blockDim.x) >> 6);
    for (int w0 = gw; w0 < NW; w0 += 4 * nw) {
        int v[4];
        #pragma unroll
        for (int i = 0; i < 4; ++i) {
            const int w = w0 + i * nw;
            v[i] = (w < NW) ? mask[(size_t)w * 64 + lane] : 0;
        }
        #pragma unroll
        for (int i = 0; i < 4; ++i) {
            const int w = w0 + i * nw;
            const u64 bb = __ballot(v[i] != 0);
            if (lane == 0 && w < NW) pm[w] = bb;
        }
    }
}

// QK+softmax of one tile -> P fragment in registers (r9's body).
#define QK_TILE(TILE, KC, MW, PDST) do {                                      \
    _Pragma("unroll")                                                         \
    for (int sub = 0; sub < 4; ++sub) {                                       \
        const short8 bk0 = *(const short8*)&(KC)[(sub*2+0)*FSTR + bsl8];      \
        const short8 bk1 = *(const short8*)&(KC)[(sub*2+1)*FSTR + bsl8];      \
        floatx4 acc = (floatx4){b_l2e, b_l2e, b_l2e, b_l2e};                  \
        acc = __builtin_amdgcn_mfma_f32_16x16x32_bf16(bk0, aq0, acc, 0,0,0);  \
        acc = __builtin_amdgcn_mfma_f32_16x16x32_bf16(bk1, aq1, acc, 0,0,0);  \
        const int sbase = 32*(sub>>1) + 4*(sub&1) + 8*quad;                   \
        unsigned mseg = 0;                                                    \
        if (PM) mseg = (unsigned)((MW) >> sbase) & 0xFu;                      \
        float pf[4];                                                          \
        _Pragma("unroll")                                                     \
        for (int r = 0; r < 4; ++r) {                                         \
            bool keep;                                                        \
            if (PM) keep = ((mseg >> r) & 1u) != 0;                           \
            else    keep = mrow[(TILE)*64 + sbase + r] != 0;                  \
            const float e = __builtin_amdgcn_exp2f(acc[r]);                   \
            pf[r] = keep ? e : 0.f;                                           \
        }                                                                     \
        (PDST)[sub*2+0] = cvt_pk_bf16(pf[0], pf[1]);                          \
        (PDST)[sub*2+1] = cvt_pk_bf16(pf[2], pf[3]);                          \
    }                                                                         \
} while (0)

// PV accumulate of one tile from a register P fragment.
#define PV_TILE(VC, PSRC) do {                                                \
    const short8 ap0 = *(const short8*)&(PSRC)[0];                            \
    const short8 ap1 = *(const short8*)&(PSRC)[4];                            \
    __builtin_amdgcn_s_setprio(1);                                            \
    _Pragma("unroll")                                                         \
    for (int csub = 0; csub < 4; ++csub) {                                    \
        const short8 bv0 = *(const short8*)&(VC)[(csub*2+0)*FSTR + bsl8];     \
        const short8 bv1 = *(const short8*)&(VC)[(csub*2+1)*FSTR + bsl8];     \
        o[csub] = __builtin_amdgcn_mfma_f32_16x16x32_bf16(ap0, bv0, o[csub],0,0,0); \
        o[csub] = __builtin_amdgcn_mfma_f32_16x16x32_bf16(ap1, bv1, o[csub],0,0,0); \
    }                                                                         \
    ol = __builtin_amdgcn_mfma_f32_16x16x32_bf16(ap0, ones8, ol, 0,0,0);      \
    ol = __builtin_amdgcn_mfma_f32_16x16x32_bf16(ap1, ones8, ol, 0,0,0);      \
    __builtin_amdgcn_s_setprio(0);                                            \
} while (0)

// K tile global load: 8 coalesced dword loads (transpose paid on the
// global side so the LDS write is ONE b128 at the fragment block).
#define K_LOAD(DST, S0) do {                                                  \
    _Pragma("unroll")                                                         \
    for (int j = 0; j < 8; ++j) (DST)[j] = kpK[j * T_LEN + (S0)];             \
} while (0)

#define K_WRITE(KD, R) do {                                                   \
    uint4 kw_;                                                                \
    kw_.x = cvt_pk_bf16((R)[0], (R)[1]);                                      \
    kw_.y = cvt_pk_bf16((R)[2], (R)[3]);                                      \
    kw_.z = cvt_pk_bf16((R)[4], (R)[5]);                                      \
    kw_.w = cvt_pk_bf16((R)[6], (R)[7]);                                      \
    *(uint4*)&(KD)[kwadrK] = kw_;                                             \
} while (0)

#define V_WRITE(VD, B0, B1) do {                                              \
    uint4 vw_;                                                                \
    vw_.x = cvt_pk_bf16((B0).x, (B0).y);                                      \
    vw_.y = cvt_pk_bf16((B0).z, (B0).w);                                      \
    vw_.z = cvt_pk_bf16((B1).x, (B1).y);                                      \
    vw_.w = cvt_pk_bf16((B1).z, (B1).w);                                      \
    *(uint4*)&(VD)[vwadr] = vw_;                                              \
} while (0)

// One block = 8 waves = 512 threads: one (head-batch, 128-row Q tile).
// r11 pipeline {QK(s+1) || PV(s) || stage(s+2 K, s+1 V)} with:
//  (1) K staged via transposed GLOBAL loads (8 coalesced dwords/thread,
//      stride-T_LEN) -> LDS write is one b128 (was 8 scattered b16);
//  (2) V double-buffered (write->read gap is exactly one barrier) with a
//      2-deep register ping-pong -> LDS back to 33280 B = 4 blocks/CU.
// Fully unrolled so all parity indices are static (no scratch).
// launch_bounds (512,2) -> 128-VGPR cap. Spill tripwire: FETCH balloon.
template<bool PM>
__global__ __launch_bounds__(512, 2)
void qkv_attn_kernel(const float* __restrict__ qkv,
                     const int* __restrict__ mask,
                     const u64* __restrict__ pm,
                     const float* __restrict__ qk_bias,
                     float* __restrict__ out)
{
    // 33280 B = 4 buffers x 4160 shorts: K0|K1|V0|V1 (tile i -> K[i&1], V[i&1]).
    // prologue: shorts 0..8191 = Q [128][LSTR] swizzled (overlaps K0|K1).
    // epilogue: Os fp32 [128][64] = 32 KB.
    __shared__ __align__(16) char smem[4 * VOFF * 2];
    short* Qs = (short*)smem;
    short* const Kb[2] = { Qs,            Qs + VOFF };
    short* const Vb[2] = { Qs + 2 * VOFF, Qs + 3 * VOFF };
    float* Os = (float*)smem;

    const int tid  = threadIdx.x;
    const int wave = tid >> 6;
    const int lane = tid & 63;
    const int quad = lane >> 4;
    const int l16  = lane & 15;

    const int bh    = blockIdx.x;   // 0..127: consecutive bh -> XCD round-robin
    const int qtile = blockIdx.y;   // 0..7:  stride-128 ids keep a bh on ONE XCD
    const int b     = bh >> 4;
    const int h     = bh & 15;
    const int t0    = qtile * 128;

    const size_t qbase = ((size_t)b * (3 * NH * CH) + (size_t)h * (3 * CH)) * T_LEN;
    const float* kp = qkv + qbase + (size_t)CH * T_LEN;
    const float* vp = qkv + qbase + (size_t)(2 * CH) * T_LEN;

    const float b_l2e  = qk_bias[0] * 1.44269504088896f;  // exp(x)=exp2(x*log2e)
    const float qscale = 0.125f * 1.44269504088896f;      // folded into Q staging

    const int c64 = tid >> 3;          // 0..63 channel row (Q/V staging)
    const int sse = (tid & 7) * 8;     // 8-s segment per thread (V staging)
    const int tse = (tid & 7) * 16;    // Q staging segment

    // K loader: wave w <-> channels 8w..8w+7, lane <-> s within the tile.
    const float* kpK = kp + (size_t)(wave * 8) * T_LEN + lane;
    const int spl = kperm(lane);
    const int kwadrK = ((spl >> 4) * 2 + (wave >> 2)) * FSTR
                     + bfold((wave & 3) * 16 + (spl & 15)) * 8;

    const float* vpr = vp + (size_t)c64 * T_LEN + sse;
    const int vwadr = ((c64 >> 4) * 2 + (sse >> 5)) * FSTR
                    + bfold(((sse >> 3) & 3) * 16 + (c64 & 15)) * 8;

    // fragment-read base (shorts): folded block of this lane, 16B-aligned
    const int bsl8 = bfold(lane) * 8;

    const int tl = t0 + wave * 16 + l16;   // lane's own t (mask row)
    const u64* pmb = PM ? pm + ((size_t)(h & 7) * T_LEN + tl) * (T_LEN / 64) : nullptr;
    const int* mrow = mask + (size_t)(h & 7) * T_LEN * T_LEN + (size_t)tl * T_LEN;

    // ---- prologue loads: K0,K1 (transposed dwords), V0,V1, masks ----
    float kr0[8], kr1[8];
    K_LOAD(kr0, 0);
    K_LOAD(kr1, 64);
    float4 v00 = *(const float4*)(vpr);
    float4 v01 = *(const float4*)(vpr + 4);
    float4 vbuf[2][2];
    vbuf[1][0] = *(const float4*)(vpr + 64);       // V1 regs (written in window 0)
    vbuf[1][1] = *(const float4*)(vpr + 68);
    u64 m0     = PM ? pmb[0] : 0ULL;
    u64 m_next = PM ? pmb[1] : 0ULL;

    // ---- stage Q transposed + swizzled + PRE-SCALED (shorts 0..8191) ----
    {
        const float* src = qkv + qbase + (size_t)c64 * T_LEN + t0 + tse;
        #pragma unroll
        for (int k = 0; k < 4; ++k) {
            float4 f = *(const float4*)(src + 4 * k);
            const int t = tse + 4 * k;
            Qs[(t + 0) * LSTR + (c64 ^ fsw(t + 0))] = f2bf(f.x * qscale);
            Qs[(t + 1) * LSTR + (c64 ^ fsw(t + 1))] = f2bf(f.y * qscale);
            Qs[(t + 2) * LSTR + (c64 ^ fsw(t + 2))] = f2bf(f.z * qscale);
            Qs[(t + 3) * LSTR + (c64 ^ fsw(t + 3))] = f2bf(f.w * qscale);
        }
    }
    __syncthreads();

    // ---- loop-invariant Q fragments (B-operand of swapped QK^T) ----
    const int qrow = wave * 16 + l16;
    const short8 aq0 = *(const short8*)&Qs[qrow * LSTR + ((quad * 8)      ^ fsw(qrow))];
    const short8 aq1 = *(const short8*)&Qs[qrow * LSTR + ((quad * 8 + 32) ^ fsw(qrow))];
    __syncthreads();   // Q region reused by K0/K1 below

    // ---- stage K0,K1,V0 ----
    K_WRITE(Kb[0], kr0);
    K_WRITE(Kb[1], kr1);
    V_WRITE(Vb[0], v00, v01);
    __syncthreads();

    const short one_bf = (short)0x3F80;
    const short8 ones8 = (short8){one_bf, one_bf, one_bf, one_bf,
                                  one_bf, one_bf, one_bf, one_bf};

    floatx4 o[4], ol;
    #pragma unroll
    for (int i = 0; i < 4; ++i) o[i] = (floatx4){0.f, 0.f, 0.f, 0.f};
    ol = (floatx4){0.f, 0.f, 0.f, 0.f};

    // ---- pipeline prime: QK(0) -> pa[0]; barrier before window 0 writes K0 ----
    unsigned pa[2][8];
    QK_TILE(0, Kb[0], m0, pa[0]);
    __syncthreads();

    // ---- steady: {QK(s+1) || PV(s) || stage K(s+2), V(s+1)}; 1 barrier ----
    #pragma unroll
    for (int s = 0; s < 15; ++s) {
        if (s + 2 <= 15) {
            K_LOAD(kr0, (s + 2) * 64);                       // K(s+2) -> regs
            vbuf[s & 1][0] = *(const float4*)(vpr + (s + 2) * 64);   // V(s+2)
            vbuf[s & 1][1] = *(const float4*)(vpr + (s + 2) * 64 + 4);
        }
        const u64 m_use = m_next;                            // mask for tile s+1
        if (PM && s + 2 <= 15) m_next = pmb[s + 2];

        QK_TILE(s + 1, Kb[(s + 1) & 1], m_use, pa[(s + 1) & 1]);
        PV_TILE(Vb[s & 1], pa[s & 1]);

        if (s + 2 <= 15) K_WRITE(Kb[s & 1], kr0);            // K(s+2)
        V_WRITE(Vb[(s + 1) & 1], vbuf[(s + 1) & 1][0], vbuf[(s + 1) & 1][1]);
        __syncthreads();
    }
    PV_TILE(Vb[15 & 1], pa[15 & 1]);                         // drain: PV(15)

    // ---- epilogue: Os fp32 [128][64] (32 KB); double-XOR swizzle ----
    __syncthreads();   // all compute done before Os overwrites K/V buffers
    float inv[4];
    #pragma unroll
    for (int r = 0; r < 4; ++r) inv[r] = (ol[r] > 0.f) ? 1.f / ol[r] : 0.f;
    const int okeyw = (wave << 3) ^ (quad << 4);
    #pragma unroll
    for (int csub = 0; csub < 4; ++csub)
        #pragma unroll
        for (int r = 0; r < 4; ++r)
            Os[(wave * 16 + quad * 4 + r) * 64 + ((csub * 16 + l16) ^ okeyw)] =
                o[csub][r] * inv[r];
    __syncthreads();
    {
        float* dst = out + ((size_t)b * (NH * CH) + (size_t)h * CH + c64) * T_LEN
                   + t0 + tse;
        #pragma unroll
        for (int k = 0; k < 4; ++k) {
            float4 f;
            #pragma unroll
            for (int j = 0; j < 4; ++j) {
                const int rl = tse + 4 * k + j;
                const int ok = ((rl >> 4) << 3) ^ (((rl >> 2) & 3) << 4);
                ((float*)&f)[j] = Os[rl * 64 + (c64 ^ ok)];
            }
            *(float4*)(dst + 4 * k) = f;
        }
    }
}

extern "C" void kernel_launch(void* const* d_in, const int* in_sizes, int n_in,
                              void* d_out, int out_size, void* d_ws, size_t ws_size,
                              hipStream_t stream) {
    const float* qkv     = (const float*)d_in[0];
    const int*   mask    = (const int*)d_in[1];
    const float* qk_bias = (const float*)d_in[2];
    float*       out     = (float*)d_out;

    const size_t pm_bytes = (size_t)8 * T_LEN * (T_LEN / 64) * sizeof(u64);  // 1 MiB
    u64* pm = nullptr;
    if (d_ws && ws_size >= pm_bytes) {
        pm = (u64*)d_ws;
        pack_mask_kernel<<<2048, 256, 0, stream>>>(mask, pm);
    }

    dim3 grid(8 * NH, T_LEN / 128);  // (head-batches, q-tiles) = (128, 8)
    if (pm) qkv_attn_kernel<true ><<<grid, 512, 0, stream>>>(qkv, mask, pm, qk_bias, out);
    else    qkv_attn_kernel<false><<<grid, 512, 0, stream>>>(qkv, mask, nullptr, qk_bias, out);
}